// Round 17
// baseline (1236.290 us; speedup 1.0000x reference)
//
#include <hip/hip_runtime.h>
#include <hip/hip_fp16.h>
#include <math.h>

#define TWO_PI_F  6.2831853071795864769f
#define INV_2PI_F 0.15915494309189533577f

constexpr int T     = 256;
constexpr int BATCH = 32;
constexpr int NIN   = 28;
constexpr int NH    = 1024;
constexpr int NOUT  = 10;

constexpr int NBLK = 32;     // 8 row-groups (128 rows each) x 4 batch-groups
constexpr int NTHR = 512;    // 8 waves: wave w = K-slice (K=128); fan-in 1

typedef unsigned int   uint;
typedef unsigned short ushort;
typedef unsigned long long ull;
typedef _Float16 half8 __attribute__((ext_vector_type(8)));
typedef float    f32x4 __attribute__((ext_vector_type(4)));

// ---- ws byte offsets ----
constexpr size_t OFF_W16 = 0;                                    // ushort [1024][1024] fp16 W = 2 MB
constexpr size_t OFF_INP = 2ull * 1024 * 1024;                   // float [T][BATCH][NH] (REVOLUTIONS) = 32 MB
constexpr size_t OFF_SCT = OFF_INP + (size_t)T * NH * BATCH * 4; // ushort [2][4][16][1024] = 256 KB
constexpr size_t OFF_STF = OFF_SCT + 2ull * 4 * 16 * 1024 * 2;   // float [BATCH][NH] = 128 KB
constexpr size_t OFF_FLG = OFF_STF + (size_t)BATCH * NH * 4;     // step flags, 8 KB

// pd row stride: 21 floats -> 16 distinct banks for m=0..15 (r15: conflicts = 0)
constexpr int PDS = 21;

// keep a value live: forces the returning atomic whose vmcnt ACK = executed-at-LLC.
__device__ __forceinline__ void sink(uint v) { asm volatile("" :: "v"(v)); }
__device__ __forceinline__ void sink64(ull v) { asm volatile("" :: "v"(v)); }

// LLC-point publish (R9/R12-proven protocol).
__device__ __forceinline__ void stx(uint* p, uint v)   { sink(atomicExch(p, v)); }
__device__ __forceinline__ void stx64(ull* p, ull v)   { sink64(atomicExch(p, v)); }

// B-fragment load: 4 x dwordx4 at 64B stride, one waitcnt (sc1 -> LLC).
__device__ __forceinline__ void ldB4(const ushort* base, uint4 bf[4]) {
  asm volatile(
    "global_load_dwordx4 %0, %4, off sc1\n\t"
    "global_load_dwordx4 %1, %4, off offset:64 sc1\n\t"
    "global_load_dwordx4 %2, %4, off offset:128 sc1\n\t"
    "global_load_dwordx4 %3, %4, off offset:192 sc1\n\t"
    "s_waitcnt vmcnt(0)"
    : "=&v"(bf[0]), "=&v"(bf[1]), "=&v"(bf[2]), "=&v"(bf[3])
    : "v"(base)
    : "memory");
}

// Per-WAVE dependency wait, fan-in ONE: wave w's K-slice (cols w*128..+127)
// is the state of units w*128..+127 = produced by exactly block rg'=w of my
// chain. Lane 0 spins; the wave cannot pass the if until the spin exits.
__device__ __forceinline__ void wave_wait1(unsigned* flags, unsigned step,
                                           int lane, int bg, int w) {
  if (lane == 0) {
    const unsigned* fp = &flags[(bg * 8 + w) * 32];
    while (__hip_atomic_load(fp, __ATOMIC_RELAXED, __HIP_MEMORY_SCOPE_AGENT) < step)
      ;   // poll period = load latency
  }
}

// Producer flag publish (R9-proven): data atomics ACKed at LLC (vmcnt drained
// by __syncthreads), then tid0 far-atomic flag.
__device__ __forceinline__ void gbar_pub(unsigned* flags, unsigned val, int tid,
                                         int rg, int bg) {
  __syncthreads();
  if (tid == 0)
    sink(atomicExch(&flags[(bg * 8 + rg) * 32], val));
}

// ---- prep: W -> fp16 ----
__global__ __launch_bounds__(256) void prep_w16(const float* __restrict__ Wh,
                                                ushort* __restrict__ w16) {
  const int m = blockIdx.x * 256 + threadIdx.x;
  w16[m] = __builtin_bit_cast(ushort, (_Float16)Wh[m]);
}

// ---- prep: inp_rev[t][b][i] = (Wi_w[i,:]·x[t,b,:] + Wi_b[i] + omega[i]) / 2pi ----
__global__ __launch_bounds__(256) void prep_inp(const float* __restrict__ x,
                                                const float* __restrict__ Wi_w,
                                                const float* __restrict__ Wi_b,
                                                const float* __restrict__ omega,
                                                float* __restrict__ inp) {
  const int t = blockIdx.x;
  const int b = blockIdx.y;
  const float* xr = x + ((size_t)t * BATCH + b) * NIN;
#pragma unroll
  for (int u = 0; u < 4; ++u) {
    const int i = u * 256 + threadIdx.x;
    const float* wr = Wi_w + (size_t)i * NIN;
    float acc = Wi_b[i] + omega[i];
#pragma unroll
    for (int k = 0; k < NIN; ++k) acc += xr[k] * wr[k];
    inp[((size_t)t * BATCH + b) * NH + i] = acc * INV_2PI_F;
  }
}

// ---- the scan: 8 blocks/chain x 128 rows, wave = K-slice, fan-in 1.
// Protocol identical to R14/R16 (per-block flags, atomic publish, hw trig).
// Two-step-lag anti-overwrite proof carries over verbatim.
__global__ __launch_bounds__(NTHR) void kuramoto_scan(
    const float*  __restrict__ inp,   // [T][BATCH][NH], revolutions
    const ushort* __restrict__ w16,   // [1024][1024] fp16
    ushort*       __restrict__ scT,   // [2][4 bg][16 n][1024 i]; n: 0-7 sin, 8-15 cos
    float*        __restrict__ stF,   // [BATCH][NH], radians (scaled at write)
    unsigned*     __restrict__ flags)
{
  // D-partials: pd[w (K-slice)][rt 0..7][n][row16 (+5 pad)]
  __shared__ float pd[8 * 8 * 16 * PDS];   // 84 KB (1 block/CU; grid 32 on 256 CUs)

  const int tid  = threadIdx.x;
  const int bid  = blockIdx.x;
  const int rg   = bid >> 2;       // row-group: units rg*128 .. +127
  const int bg   = bid & 3;        // batch-group: batches bg*8 .. +7
  const int lane = tid & 63;
  const int w    = tid >> 6;       // K-slice 0..7
  const int m    = lane & 15;      // A: M index / B,D: N index
  const int quad = lane >> 4;

  // ---- A-fragments: rows {rt*16+m, rt=0..7} x K-slice w: 32 frags x 4 VGPR ----
  half8 af[32];
  {
    const ushort* wbase = w16 + (size_t)(rg * 128 + m) * NH + w * 128 + quad * 8;
#pragma unroll
    for (int rt = 0; rt < 8; ++rt)
#pragma unroll
      for (int j = 0; j < 4; ++j)
        af[rt * 4 + j] = __builtin_bit_cast(half8,
            *(const uint4*)(wbase + (size_t)rt * 16 * NH + j * 32));
  }

  // ---- theta-phase identity: 2 units per thread (ilc and ilc+64) ----
  const int bl = tid >> 6;         // 0..7 (== w)
  const int ilc = tid & 63;        // 0..63
  const int i0 = rg * 128 + ilc;         // unit group 0
  const int i1 = i0 + 64;                // unit group 1
  const int b  = bg * 8 + bl;            // my batch
  float th0 = 0.f, s0 = 0.f, c0 = 1.f;   // th in REVOLUTIONS
  float th1 = 0.f, s1 = 0.f, c1 = 1.f;

  // ---- init parity-0 state for both unit groups (32-bit far atomics) ----
  {
    const size_t r0 = (size_t)(0 * 4 + bg) * 16;
    if ((ilc & 1) == 0) {
      stx((uint*)(scT + (r0 + bl) * 1024 + i0), 0x00000000u);             // sin = 0,0
      stx((uint*)(scT + (r0 + bl) * 1024 + i1), 0x00000000u);
    } else {
      stx((uint*)(scT + (r0 + bl + 8) * 1024 + (i0 - 1)), 0x3C003C00u);   // cos = 1,1
      stx((uint*)(scT + (r0 + bl + 8) * 1024 + (i1 - 1)), 0x3C003C00u);
    }
  }

  unsigned step = 1;
  gbar_pub(flags, step, tid, rg, bg);      // flag 1 guards iteration-0 reads
  float inpv0 = inp[(size_t)b * NH + i0];  // t=0 prefetch drains under the wait
  float inpv1 = inp[(size_t)b * NH + i1];

  for (int t = 0; t < T; ++t) {
    const int p = t & 1;

    // ---- wait on MY ONE producer block, then load my B-slice ----
    wave_wait1(flags, step, lane, bg, w);
    uint4 bf[4];
    ldB4(scT + ((size_t)(p * 4 + bg) * 16 + m) * 1024 + w * 128 + quad * 8, bf);

    // ---- MFMA: 8 row-tiles x K=128, in two halves of 4 accumulators ----
    {
      f32x4 D0 = {0.f,0.f,0.f,0.f}, D1 = {0.f,0.f,0.f,0.f};
      f32x4 D2 = {0.f,0.f,0.f,0.f}, D3 = {0.f,0.f,0.f,0.f};
#pragma unroll
      for (int j = 0; j < 4; ++j) {
        const half8 bh = __builtin_bit_cast(half8, bf[j]);
        D0 = __builtin_amdgcn_mfma_f32_16x16x32_f16(af[0 * 4 + j], bh, D0, 0, 0, 0);
        D1 = __builtin_amdgcn_mfma_f32_16x16x32_f16(af[1 * 4 + j], bh, D1, 0, 0, 0);
        D2 = __builtin_amdgcn_mfma_f32_16x16x32_f16(af[2 * 4 + j], bh, D2, 0, 0, 0);
        D3 = __builtin_amdgcn_mfma_f32_16x16x32_f16(af[3 * 4 + j], bh, D3, 0, 0, 0);
      }
      *(f32x4*)&pd[(((w * 8 + 0) * 16) + m) * PDS + quad * 4] = D0;
      *(f32x4*)&pd[(((w * 8 + 1) * 16) + m) * PDS + quad * 4] = D1;
      *(f32x4*)&pd[(((w * 8 + 2) * 16) + m) * PDS + quad * 4] = D2;
      *(f32x4*)&pd[(((w * 8 + 3) * 16) + m) * PDS + quad * 4] = D3;
    }
    {
      f32x4 D4 = {0.f,0.f,0.f,0.f}, D5 = {0.f,0.f,0.f,0.f};
      f32x4 D6 = {0.f,0.f,0.f,0.f}, D7 = {0.f,0.f,0.f,0.f};
#pragma unroll
      for (int j = 0; j < 4; ++j) {
        const half8 bh = __builtin_bit_cast(half8, bf[j]);
        D4 = __builtin_amdgcn_mfma_f32_16x16x32_f16(af[4 * 4 + j], bh, D4, 0, 0, 0);
        D5 = __builtin_amdgcn_mfma_f32_16x16x32_f16(af[5 * 4 + j], bh, D5, 0, 0, 0);
        D6 = __builtin_amdgcn_mfma_f32_16x16x32_f16(af[6 * 4 + j], bh, D6, 0, 0, 0);
        D7 = __builtin_amdgcn_mfma_f32_16x16x32_f16(af[7 * 4 + j], bh, D7, 0, 0, 0);
      }
      *(f32x4*)&pd[(((w * 8 + 4) * 16) + m) * PDS + quad * 4] = D4;
      *(f32x4*)&pd[(((w * 8 + 5) * 16) + m) * PDS + quad * 4] = D5;
      *(f32x4*)&pd[(((w * 8 + 6) * 16) + m) * PDS + quad * 4] = D6;
      *(f32x4*)&pd[(((w * 8 + 7) * 16) + m) * PDS + quad * 4] = D7;
    }
    __syncthreads();   // all waves' pd ready AND all 8 flags >= step observed

    // ---- theta update for 2 units (revolutions, hw trig) ----
    const int rti0 = ilc >> 4;          // 0..3
    const int rti1 = rti0 + 4;          // 4..7
    const int r16  = ilc & 15;
    float S0 = 0.f, C0 = 0.f, S1 = 0.f, C1 = 0.f;
#pragma unroll
    for (int ww = 0; ww < 8; ++ww) {
      S0 += pd[((ww * 8 + rti0) * 16 + bl) * PDS + r16];
      C0 += pd[((ww * 8 + rti0) * 16 + bl + 8) * PDS + r16];
      S1 += pd[((ww * 8 + rti1) * 16 + bl) * PDS + r16];
      C1 += pd[((ww * 8 + rti1) * 16 + bl + 8) * PDS + r16];
    }
    {
      const float coup0 = s0 * C0 - c0 * S0;
      const float thn0 = th0 + coup0 * INV_2PI_F + inpv0;
      asm("v_fract_f32 %0, %1" : "=v"(th0) : "v"(thn0));
      asm("v_sin_f32 %0, %1" : "=v"(s0) : "v"(th0));
      asm("v_cos_f32 %0, %1" : "=v"(c0) : "v"(th0));
      const float coup1 = s1 * C1 - c1 * S1;
      const float thn1 = th1 + coup1 * INV_2PI_F + inpv1;
      asm("v_fract_f32 %0, %1" : "=v"(th1) : "v"(thn1));
      asm("v_sin_f32 %0, %1" : "=v"(s1) : "v"(th1));
      asm("v_cos_f32 %0, %1" : "=v"(c1) : "v"(th1));
    }

    if (t == T - 1) break;

    // ---- publish fp16 state for both unit groups: packed 64-bit far atomics ----
    const size_t dbase = (size_t)((p ^ 1) * 4 + bg) * 16;
    {
      const uint hs = __builtin_bit_cast(ushort, (_Float16)s0);
      const uint hc = __builtin_bit_cast(ushort, (_Float16)c0);
      const uint phs = (uint)__shfl_xor((int)hs, 1, 64);
      const uint phc = (uint)__shfl_xor((int)hc, 1, 64);
      const uint pw = hs | (phs << 16), cw = phc | (hc << 16);
      const uint pw2 = (uint)__shfl_xor((int)pw, 2, 64);
      const uint cw2 = (uint)__shfl_xor((int)cw, 2, 64);
      if ((ilc & 3) == 0)
        stx64((ull*)(scT + (dbase + bl) * 1024 + i0), (ull)pw | ((ull)pw2 << 32));
      else if ((ilc & 3) == 1)
        stx64((ull*)(scT + (dbase + bl + 8) * 1024 + (i0 - 1)), (ull)cw | ((ull)cw2 << 32));
    }
    {
      const uint hs = __builtin_bit_cast(ushort, (_Float16)s1);
      const uint hc = __builtin_bit_cast(ushort, (_Float16)c1);
      const uint phs = (uint)__shfl_xor((int)hs, 1, 64);
      const uint phc = (uint)__shfl_xor((int)hc, 1, 64);
      const uint pw = hs | (phs << 16), cw = phc | (hc << 16);
      const uint pw2 = (uint)__shfl_xor((int)pw, 2, 64);
      const uint cw2 = (uint)__shfl_xor((int)cw, 2, 64);
      if ((ilc & 3) == 0)
        stx64((ull*)(scT + (dbase + bl) * 1024 + i1), (ull)pw | ((ull)pw2 << 32));
      else if ((ilc & 3) == 1)
        stx64((ull*)(scT + (dbase + bl + 8) * 1024 + (i1 - 1)), (ull)cw | ((ull)cw2 << 32));
    }

    gbar_pub(flags, step + 1, tid, rg, bg);                // flag guards t+1 reads
    inpv0 = inp[((size_t)(t + 1) * BATCH + b) * NH + i0];  // drains under next wait
    inpv1 = inp[((size_t)(t + 1) * BATCH + b) * NH + i1];
    ++step;
  }

  stF[(size_t)b * NH + i0] = th0 * TWO_PI_F;   // revolutions -> radians
  stF[(size_t)b * NH + i1] = th1 * TWO_PI_F;
}

// ---- readout ----
__global__ void readout(const float* __restrict__ stF,
                        const float* __restrict__ Wout,   // [10][1024]
                        const float* __restrict__ bout,   // [10]
                        float* __restrict__ out)          // [32][10]
{
  const int bb = blockIdx.x;
  const int lane = threadIdx.x;   // 64 threads
  float st[16];
#pragma unroll
  for (int u = 0; u < 16; ++u) st[u] = stF[(size_t)bb * NH + u * 64 + lane];
  for (int o = 0; o < NOUT; ++o) {
    float acc = 0.f;
#pragma unroll
    for (int u = 0; u < 16; ++u) acc += st[u] * Wout[o * NH + u * 64 + lane];
#pragma unroll
    for (int sh = 1; sh < 64; sh <<= 1) acc += __shfl_xor(acc, sh, 64);
    if (lane == 0) out[bb * NOUT + o] = acc + bout[o];
  }
}

extern "C" void kernel_launch(void* const* d_in, const int* in_sizes, int n_in,
                              void* d_out, int out_size, void* d_ws, size_t ws_size,
                              hipStream_t stream) {
  const float* x     = (const float*)d_in[0];
  const float* Wi_w  = (const float*)d_in[1];
  const float* Wi_b  = (const float*)d_in[2];
  const float* Wh    = (const float*)d_in[3];
  const float* omega = (const float*)d_in[4];
  const float* W_out = (const float*)d_in[5];
  const float* b_out = (const float*)d_in[6];

  char* ws = (char*)d_ws;
  ushort*   w16 = (ushort*)(ws + OFF_W16);
  float*    inp = (float*)(ws + OFF_INP);
  ushort*   scT = (ushort*)(ws + OFF_SCT);
  float*    stF = (float*)(ws + OFF_STF);
  unsigned* flg = (unsigned*)(ws + OFF_FLG);

  (void)hipMemsetAsync(ws + OFF_FLG, 0, 8192, stream);

  prep_w16<<<dim3(NH * NH / 256), dim3(256), 0, stream>>>(Wh, w16);
  prep_inp<<<dim3(T, BATCH), dim3(256), 0, stream>>>(x, Wi_w, Wi_b, omega, inp);

  void* args[] = { (void*)&inp, (void*)&w16, (void*)&scT, (void*)&stF, (void*)&flg };
  hipError_t err = hipLaunchCooperativeKernel((const void*)kuramoto_scan,
                                              dim3(NBLK), dim3(NTHR), args, 0, stream);
  if (err != hipSuccess) {
    // 32 blocks at 1 block/CU are trivially co-resident; normal launch is safe.
    (void)hipGetLastError();
    kuramoto_scan<<<dim3(NBLK), dim3(NTHR), 0, stream>>>(inp, w16, scT, stF, flg);
  }

  readout<<<dim3(BATCH), dim3(64), 0, stream>>>(stF, W_out, b_out, (float*)d_out);
}